// Round 1
// baseline (2989.359 us; speedup 1.0000x reference)
//
#include <hip/hip_runtime.h>
#include <math.h>

#define T_SEQ 2048
#define DMODEL 2048
#define DSTATE 128
#define NH 64
#define NG 8
#define HPG 8
#define HD 64
#define CH 256
#define NC 8
#define DIN 4096
#define CONVD 6144
#define DPROJ 10304
#define EPS 1e-5f

__device__ __forceinline__ float silu_f(float x) { return x / (1.0f + __expf(-x)); }

// ---------------- GEMM: C[M,N] = A[M,K] * B[N,K]^T (both row-major, K contiguous)
__global__ __launch_bounds__(256) void gemm_nt(const float* __restrict__ A,
                                               const float* __restrict__ B,
                                               float* __restrict__ C,
                                               int M, int N, int K) {
    __shared__ float As[16][68];
    __shared__ float Bs[16][68];
    const int tid = threadIdx.x;
    const int n0 = blockIdx.x * 64, m0 = blockIdx.y * 64;
    const int lk = tid & 15, lr = tid >> 4;   // load: k-within-tile, row
    const int ty = tid >> 4, tx = tid & 15;   // compute: 16x16 grid of 4x4 microtiles
    float acc[4][4] = {};
    for (int k0 = 0; k0 < K; k0 += 16) {
#pragma unroll
        for (int i = 0; i < 4; ++i) {
            As[lk][lr + 16 * i] = A[(m0 + lr + 16 * i) * (size_t)K + k0 + lk];
            Bs[lk][lr + 16 * i] = B[(n0 + lr + 16 * i) * (size_t)K + k0 + lk];
        }
        __syncthreads();
#pragma unroll
        for (int kk = 0; kk < 16; ++kk) {
            const float4 av = *(const float4*)&As[kk][ty * 4];
            const float4 bv = *(const float4*)&Bs[kk][tx * 4];
            const float a[4] = {av.x, av.y, av.z, av.w};
            const float b[4] = {bv.x, bv.y, bv.z, bv.w};
#pragma unroll
            for (int i = 0; i < 4; ++i)
#pragma unroll
                for (int j = 0; j < 4; ++j)
                    acc[i][j] = fmaf(a[i], b[j], acc[i][j]);
        }
        __syncthreads();
    }
#pragma unroll
    for (int i = 0; i < 4; ++i)
#pragma unroll
        for (int j = 0; j < 4; ++j)
            C[(m0 + ty * 4 + i) * (size_t)N + n0 + tx * 4 + j] = acc[i][j];
}

// ---------------- causal conv1d (width 4) + SiLU over the xBC slice of zxbcdt
__global__ __launch_bounds__(256) void conv_kernel(const float* __restrict__ zx,
                                                   const float* __restrict__ cw,
                                                   const float* __restrict__ cb,
                                                   float* __restrict__ xconv) {
    int idx = blockIdx.x * 256 + threadIdx.x;  // over T_SEQ*CONVD
    int c = idx % CONVD, t = idx / CONVD;
    float acc = cb[c];
#pragma unroll
    for (int k = 0; k < 4; ++k) {
        int tt = t + k - 3;
        float v = (tt >= 0) ? zx[(size_t)tt * DPROJ + DIN + c] : 0.0f;
        acc = fmaf(v, cw[c * 4 + k], acc);
    }
    xconv[idx] = silu_f(acc);
}

// ---------------- dt = softplus(dt_raw + bias); dA_cs = cumsum(dt*A) within chunk
// stored transposed: dt_s[h*T + t], dAcs[h*T + t]
__global__ __launch_bounds__(256) void dt_kernel(const float* __restrict__ zx,
                                                 const float* __restrict__ A,
                                                 const float* __restrict__ dt_bias,
                                                 float* __restrict__ dt_s,
                                                 float* __restrict__ dAcs) {
    __shared__ float s[CH];
    int h = blockIdx.x % NH, c = blockIdx.x / NH;
    int t = threadIdx.x;
    int tg = c * CH + t;
    float raw = zx[(size_t)tg * DPROJ + DIN + CONVD + h] + dt_bias[h];
    float dtv = (raw > 20.0f) ? raw : log1pf(__expf(raw));
    s[t] = dtv * A[h];
    __syncthreads();
    for (int off = 1; off < CH; off <<= 1) {
        float add = (t >= off) ? s[t - off] : 0.0f;
        __syncthreads();
        s[t] += add;
        __syncthreads();
    }
    dt_s[h * T_SEQ + tg] = dtv;
    dAcs[h * T_SEQ + tg] = s[t];
}

// ---------------- CB[c,g,s,t] = sum_n C[c,s,g,n] * B[c,t,g,n]
__global__ __launch_bounds__(256) void cb_kernel(const float* __restrict__ xconv,
                                                 float* __restrict__ CB) {
    __shared__ float crow[DSTATE];
    int s = blockIdx.x % CH;
    int g = (blockIdx.x / CH) % NG;
    int c = blockIdx.x / (CH * NG);
    int tid = threadIdx.x;
    if (tid < DSTATE)
        crow[tid] = xconv[(size_t)(c * CH + s) * CONVD + DIN + NG * DSTATE + g * DSTATE + tid];
    __syncthreads();
    const float4* b4 = (const float4*)&xconv[(size_t)(c * CH + tid) * CONVD + DIN + g * DSTATE];
    float dot = 0.0f;
#pragma unroll
    for (int n = 0; n < DSTATE / 4; ++n) {
        float4 b = b4[n];
        float4 cc = *(const float4*)&crow[n * 4];
        dot = fmaf(b.x, cc.x, dot);
        dot = fmaf(b.y, cc.y, dot);
        dot = fmaf(b.z, cc.z, dot);
        dot = fmaf(b.w, cc.w, dot);
    }
    CB[(size_t)blockIdx.x * CH + tid] = dot;
}

// ---------------- intra-chunk: Y1[c,s,h,p] = sum_{t<=s} CB*exp(dA_s-dA_t)*dt_t*x[t,h,p] + D*x[s,h,p]
__global__ __launch_bounds__(64) void y1_kernel(const float* __restrict__ xconv,
                                                const float* __restrict__ CB,
                                                const float* __restrict__ dt_s,
                                                const float* __restrict__ dAcs,
                                                const float* __restrict__ Dp,
                                                float* __restrict__ yacc) {
    __shared__ float s_cb[CH], s_da[CH], s_dt[CH];
    int s = blockIdx.x % CH;
    int h = (blockIdx.x / CH) % NH;
    int c = blockIdx.x / (CH * NH);
    int g = h >> 3;
    int p = threadIdx.x;
    const float* cbrow = &CB[(size_t)((c * NG + g) * CH + s) * CH];
    for (int i = p; i < CH; i += 64) {
        s_cb[i] = cbrow[i];
        s_da[i] = dAcs[h * T_SEQ + c * CH + i];
        s_dt[i] = dt_s[h * T_SEQ + c * CH + i];
    }
    __syncthreads();
    float das = s_da[s];
    float acc = 0.0f;
    for (int t = 0; t <= s; ++t) {
        float w = s_cb[t] * __expf(das - s_da[t]) * s_dt[t];
        acc = fmaf(w, xconv[(size_t)(c * CH + t) * CONVD + h * HD + p], acc);
    }
    acc = fmaf(Dp[h], xconv[(size_t)(c * CH + s) * CONVD + h * HD + p], acc);
    yacc[(size_t)(c * CH + s) * DIN + h * HD + p] = acc;
}

// ---------------- states[c,h,p,n] = sum_t B[c,t,g,n] * exp(dA_last-dA_t)*dt_t * x[c,t,h,p]
__global__ __launch_bounds__(256) void states_kernel(const float* __restrict__ xconv,
                                                     const float* __restrict__ dt_s,
                                                     const float* __restrict__ dAcs,
                                                     float* __restrict__ states) {
    __shared__ float bsh[CH * DSTATE];  // 128 KB
    __shared__ float w2sh[CH];
    int h = blockIdx.x % NH, c = blockIdx.x / NH;
    int g = h >> 3;
    int tid = threadIdx.x;
    for (int i = 0; i < (CH * DSTATE) / 256; ++i) {
        int flat = i * 256 + tid;
        int t = flat / DSTATE, n = flat % DSTATE;
        bsh[flat] = xconv[(size_t)(c * CH + t) * CONVD + DIN + g * DSTATE + n];
    }
    float da_last = dAcs[h * T_SEQ + c * CH + CH - 1];
    w2sh[tid] = __expf(da_last - dAcs[h * T_SEQ + c * CH + tid]) * dt_s[h * T_SEQ + c * CH + tid];
    __syncthreads();
    int p = tid & 63, nb = (tid >> 6) * 32;
    float acc[32] = {};
    for (int t = 0; t < CH; ++t) {
        float wx = w2sh[t] * xconv[(size_t)(c * CH + t) * CONVD + h * HD + p];
        const float* br = &bsh[t * DSTATE + nb];
#pragma unroll
        for (int j = 0; j < 32; ++j) acc[j] = fmaf(wx, br[j], acc[j]);
    }
    float* so = &states[((size_t)(c * NH + h) * HD + p) * DSTATE + nb];
#pragma unroll
    for (int j = 0; j < 32; ++j) so[j] = acc[j];
}

// ---------------- sequential chunk scan: prev[c] = carry before chunk c
__global__ __launch_bounds__(256) void scan_kernel(const float* __restrict__ states,
                                                   const float* __restrict__ dAcs,
                                                   float* __restrict__ prev) {
    int h = blockIdx.x;
    int base = threadIdx.x * 32;
    float carry[32] = {};
    for (int c = 0; c < NC; ++c) {
        size_t off = (size_t)(c * NH + h) * (HD * DSTATE) + base;
#pragma unroll
        for (int j = 0; j < 32; ++j) prev[off + j] = carry[j];
        float cd = __expf(dAcs[h * T_SEQ + c * CH + CH - 1]);
#pragma unroll
        for (int j = 0; j < 32; ++j) carry[j] = fmaf(carry[j], cd, states[off + j]);
    }
}

// ---------------- Y2: yacc[c,s,h,p] += exp(dAcs[s]) * sum_n C[c,s,g,n]*prev[c,h,p,n]
__global__ __launch_bounds__(256) void y2_kernel(const float* __restrict__ xconv,
                                                 const float* __restrict__ prev,
                                                 const float* __restrict__ dAcs,
                                                 float* __restrict__ yacc) {
    __shared__ float psh[DSTATE * 65];  // transposed + padded: psh[n*65+p]
    int h = blockIdx.x % NH, c = blockIdx.x / NH;
    int g = h >> 3;
    int tid = threadIdx.x;
    size_t pbase = (size_t)(c * NH + h) * (HD * DSTATE);
    for (int i = 0; i < 32; ++i) {
        int flat = i * 256 + tid;
        int p = flat >> 7, n = flat & 127;
        psh[n * 65 + p] = prev[pbase + flat];
    }
    __syncthreads();
    int p = tid & 63, sq = tid >> 6;
    for (int si = 0; si < 64; ++si) {
        int s = sq * 64 + si;
        const float* crow = &xconv[(size_t)(c * CH + s) * CONVD + DIN + NG * DSTATE + g * DSTATE];
        float dot = 0.0f;
#pragma unroll 8
        for (int n = 0; n < DSTATE; ++n) dot = fmaf(crow[n], psh[n * 65 + p], dot);
        float e = __expf(dAcs[h * T_SEQ + c * CH + s]);
        size_t yi = (size_t)(c * CH + s) * DIN + h * HD + p;
        yacc[yi] += e * dot;
    }
}

// ---------------- gate with silu(z), grouped RMSNorm (groups of 512)
__global__ __launch_bounds__(256) void norm_kernel(const float* __restrict__ zx,
                                                   const float* __restrict__ yacc,
                                                   const float* __restrict__ norm_w,
                                                   float* __restrict__ ynorm) {
    __shared__ float red[4];
    int t = blockIdx.x / NG, g = blockIdx.x % NG;
    int tid = threadIdx.x;
    int j1 = g * 512 + tid, j2 = j1 + 256;
    float v1 = yacc[(size_t)t * DIN + j1] * silu_f(zx[(size_t)t * DPROJ + j1]);
    float v2 = yacc[(size_t)t * DIN + j2] * silu_f(zx[(size_t)t * DPROJ + j2]);
    float ss = v1 * v1 + v2 * v2;
#pragma unroll
    for (int off = 32; off > 0; off >>= 1) ss += __shfl_down(ss, off, 64);
    if ((tid & 63) == 0) red[tid >> 6] = ss;
    __syncthreads();
    float var = (red[0] + red[1] + red[2] + red[3]) * (1.0f / 512.0f);
    float scale = rsqrtf(var + EPS);
    ynorm[(size_t)t * DIN + j1] = v1 * scale * norm_w[j1];
    ynorm[(size_t)t * DIN + j2] = v2 * scale * norm_w[j2];
}

extern "C" void kernel_launch(void* const* d_in, const int* in_sizes, int n_in,
                              void* d_out, int out_size, void* d_ws, size_t ws_size,
                              hipStream_t stream) {
    const float* hidden     = (const float*)d_in[0];
    const float* in_proj_w  = (const float*)d_in[1];
    const float* conv_w     = (const float*)d_in[2];
    const float* conv_b     = (const float*)d_in[3];
    const float* A          = (const float*)d_in[4];
    const float* Dp         = (const float*)d_in[5];
    const float* dt_bias    = (const float*)d_in[6];
    const float* norm_w     = (const float*)d_in[7];
    const float* out_proj_w = (const float*)d_in[8];
    float* out = (float*)d_out;

    float* ws    = (float*)d_ws;
    float* zx    = ws;                            // T*DPROJ      = 21,102,592
    float* xconv = zx + (size_t)T_SEQ * DPROJ;    // T*CONVD      = 12,582,912
    float* dt_s  = xconv + (size_t)T_SEQ * CONVD; // NH*T         = 131,072
    float* dAcs  = dt_s + (size_t)NH * T_SEQ;     // NH*T         = 131,072
    float* CBbuf = dAcs + (size_t)NH * T_SEQ;     // NC*NG*CH*CH  = 4,194,304
    float* yacc  = CBbuf + (size_t)NC * NG * CH * CH; // T*DIN    = 8,388,608
    float* prev  = yacc + (size_t)T_SEQ * DIN;    // NC*NH*HD*DS  = 4,194,304
    float* states = CBbuf;   // alias: CB dead after y1_kernel
    float* ynorm  = xconv;   // alias: xconv dead after y2_kernel

    gemm_nt<<<dim3(DPROJ / 64, T_SEQ / 64), 256, 0, stream>>>(hidden, in_proj_w, zx, T_SEQ, DPROJ, DMODEL);
    conv_kernel<<<(T_SEQ * CONVD) / 256, 256, 0, stream>>>(zx, conv_w, conv_b, xconv);
    dt_kernel<<<NC * NH, CH, 0, stream>>>(zx, A, dt_bias, dt_s, dAcs);
    cb_kernel<<<NC * NG * CH, CH, 0, stream>>>(xconv, CBbuf);
    y1_kernel<<<NC * NH * CH, 64, 0, stream>>>(xconv, CBbuf, dt_s, dAcs, Dp, yacc);
    states_kernel<<<NC * NH, 256, 0, stream>>>(xconv, dt_s, dAcs, states);
    scan_kernel<<<NH, 256, 0, stream>>>(states, dAcs, prev);
    y2_kernel<<<NC * NH, 256, 0, stream>>>(xconv, prev, dAcs, yacc);
    norm_kernel<<<T_SEQ * NG, 256, 0, stream>>>(zx, yacc, norm_w, ynorm);
    gemm_nt<<<dim3(DMODEL / 64, T_SEQ / 64), 256, 0, stream>>>(ynorm, out_proj_w, out, T_SEQ, DMODEL, DIN);
}

// Round 2
// 1398.802 us; speedup vs baseline: 2.1371x; 2.1371x over previous
//
#include <hip/hip_runtime.h>
#include <math.h>

#define T_SEQ 2048
#define DMODEL 2048
#define DSTATE 128
#define NH 64
#define NG 8
#define HPG 8
#define HD 64
#define CH 256
#define NC 8
#define DIN 4096
#define CONVD 6144
#define DPROJ 10304
#define DPROJP 10368   // padded to 81*128 for 128-wide MFMA tiles
#define EPS 1e-5f

typedef short v8s __attribute__((ext_vector_type(8)));
typedef float v4f __attribute__((ext_vector_type(4)));

__device__ __forceinline__ float silu_f(float x) { return x / (1.0f + __expf(-x)); }

__device__ __forceinline__ unsigned short f2b(float x) {  // fp32 -> bf16 bits, RNE
    union { float f; unsigned u; } v; v.f = x;
    unsigned r = v.u + 0x7fffu + ((v.u >> 16) & 1u);
    return (unsigned short)(r >> 16);
}

// ---------------- fp32 -> bf16 convert (flat, with zero tail-padding), 4 elems/thread
__global__ __launch_bounds__(256) void cvt4_kernel(const float4* __restrict__ src,
                                                   ushort4* __restrict__ dst,
                                                   int n4_src, int n4_dst) {
    int i = blockIdx.x * 256 + threadIdx.x;
    if (i >= n4_dst) return;
    ushort4 o = {0, 0, 0, 0};
    if (i < n4_src) {
        float4 v = src[i];
        o.x = f2b(v.x); o.y = f2b(v.y); o.z = f2b(v.z); o.w = f2b(v.w);
    }
    dst[i] = o;
}

// ---------------- bf16 MFMA GEMM: C[M,N] = A[M,K] * B[N,K]^T, fp32 out
// BM=128 fixed, BN template (128 or 64). 256 threads = 4 waves in 2x2.
template <int BN>
__global__ __launch_bounds__(256) void gemm_bf16(const unsigned short* __restrict__ A,
                                                 const unsigned short* __restrict__ B,
                                                 float* __restrict__ C,
                                                 int M, int N, int K) {
    constexpr int BM = 128, BK = 32;
    constexpr int NWT = BN / 32;                 // B-frags per wave
    constexpr int BCH = (BN * BK * 2) / 1024;    // B staging chunks (1KB each)
    __shared__ short sA[BM * BK];
    __shared__ short sB[BN * BK];
    const int tid = threadIdx.x;
    const int wave = tid >> 6, lane = tid & 63;
    const int n0 = blockIdx.x * BN, m0 = blockIdx.y * BM;
    const int wm = (wave >> 1) * 64;
    const int wn = (wave & 1) * (BN / 2);
    const int lr = lane & 15, kq = lane >> 4;

    v4f acc[4][NWT];
#pragma unroll
    for (int i = 0; i < 4; ++i)
#pragma unroll
        for (int j = 0; j < NWT; ++j) acc[i][j] = {0.f, 0.f, 0.f, 0.f};

    for (int k0 = 0; k0 < K; k0 += BK) {
        // stage A: 8 chunks of 1KB (16 rows each), 2 per wave
#pragma unroll
        for (int qi = 0; qi < 2; ++qi) {
            int q = wave * 2 + qi;
            int e = q * 512 + lane * 8;          // flat bf16 element
            int r = e >> 5, c = e & 31;
            __builtin_amdgcn_global_load_lds(
                (const __attribute__((address_space(1))) void*)(A + (size_t)(m0 + r) * K + k0 + c),
                (__attribute__((address_space(3))) void*)(sA + q * 512), 16, 0, 0);
        }
        // stage B: BCH chunks
        for (int q = wave; q < BCH; q += 4) {
            int e = q * 512 + lane * 8;
            int r = e >> 5, c = e & 31;
            __builtin_amdgcn_global_load_lds(
                (const __attribute__((address_space(1))) void*)(B + (size_t)(n0 + r) * K + k0 + c),
                (__attribute__((address_space(3))) void*)(sB + q * 512), 16, 0, 0);
        }
        __syncthreads();
        v8s af[4], bf[NWT];
#pragma unroll
        for (int i = 0; i < 4; ++i)
            af[i] = *(const v8s*)(sA + (wm + i * 16 + lr) * BK + kq * 8);
#pragma unroll
        for (int j = 0; j < NWT; ++j)
            bf[j] = *(const v8s*)(sB + (wn + j * 16 + lr) * BK + kq * 8);
#pragma unroll
        for (int i = 0; i < 4; ++i)
#pragma unroll
            for (int j = 0; j < NWT; ++j)
                acc[i][j] = __builtin_amdgcn_mfma_f32_16x16x32_bf16(af[i], bf[j], acc[i][j], 0, 0, 0);
        __syncthreads();
    }
    // C/D layout: col = lane&15, row = (lane>>4)*4 + reg
    const int crow = kq * 4, ccol = lr;
#pragma unroll
    for (int i = 0; i < 4; ++i)
#pragma unroll
        for (int j = 0; j < NWT; ++j) {
            size_t base = (size_t)(m0 + wm + i * 16 + crow) * N + n0 + wn + j * 16 + ccol;
#pragma unroll
            for (int r = 0; r < 4; ++r) C[base + (size_t)r * N] = acc[i][j][r];
        }
}

// ---------------- causal conv1d (width 4) + SiLU over the xBC slice of zxbcdt
__global__ __launch_bounds__(256) void conv_kernel(const float* __restrict__ zx,
                                                   const float* __restrict__ cw,
                                                   const float* __restrict__ cb,
                                                   float* __restrict__ xconv) {
    int idx = blockIdx.x * 256 + threadIdx.x;  // over T_SEQ*CONVD
    int c = idx % CONVD, t = idx / CONVD;
    float acc = cb[c];
#pragma unroll
    for (int k = 0; k < 4; ++k) {
        int tt = t + k - 3;
        float v = (tt >= 0) ? zx[(size_t)tt * DPROJP + DIN + c] : 0.0f;
        acc = fmaf(v, cw[c * 4 + k], acc);
    }
    xconv[idx] = silu_f(acc);
}

// ---------------- dt = softplus(dt_raw + bias); dA_cs = cumsum(dt*A) within chunk
__global__ __launch_bounds__(256) void dt_kernel(const float* __restrict__ zx,
                                                 const float* __restrict__ A,
                                                 const float* __restrict__ dt_bias,
                                                 float* __restrict__ dt_s,
                                                 float* __restrict__ dAcs) {
    __shared__ float s[CH];
    int h = blockIdx.x % NH, c = blockIdx.x / NH;
    int t = threadIdx.x;
    int tg = c * CH + t;
    float raw = zx[(size_t)tg * DPROJP + DIN + CONVD + h] + dt_bias[h];
    float dtv = (raw > 20.0f) ? raw : log1pf(__expf(raw));
    s[t] = dtv * A[h];
    __syncthreads();
    for (int off = 1; off < CH; off <<= 1) {
        float add = (t >= off) ? s[t - off] : 0.0f;
        __syncthreads();
        s[t] += add;
        __syncthreads();
    }
    dt_s[h * T_SEQ + tg] = dtv;
    dAcs[h * T_SEQ + tg] = s[t];
}

// ---------------- CB[c,g,s,t] = sum_n C[c,s,g,n] * B[c,t,g,n]
__global__ __launch_bounds__(256) void cb_kernel(const float* __restrict__ xconv,
                                                 float* __restrict__ CB) {
    __shared__ float crow[DSTATE];
    int s = blockIdx.x % CH;
    int g = (blockIdx.x / CH) % NG;
    int c = blockIdx.x / (CH * NG);
    int tid = threadIdx.x;
    if (tid < DSTATE)
        crow[tid] = xconv[(size_t)(c * CH + s) * CONVD + DIN + NG * DSTATE + g * DSTATE + tid];
    __syncthreads();
    const float4* b4 = (const float4*)&xconv[(size_t)(c * CH + tid) * CONVD + DIN + g * DSTATE];
    float dot = 0.0f;
#pragma unroll
    for (int n = 0; n < DSTATE / 4; ++n) {
        float4 b = b4[n];
        float4 cc = *(const float4*)&crow[n * 4];
        dot = fmaf(b.x, cc.x, dot);
        dot = fmaf(b.y, cc.y, dot);
        dot = fmaf(b.z, cc.z, dot);
        dot = fmaf(b.w, cc.w, dot);
    }
    CB[(size_t)blockIdx.x * CH + tid] = dot;
}

// ---------------- intra-chunk scan
__global__ __launch_bounds__(64) void y1_kernel(const float* __restrict__ xconv,
                                                const float* __restrict__ CB,
                                                const float* __restrict__ dt_s,
                                                const float* __restrict__ dAcs,
                                                const float* __restrict__ Dp,
                                                float* __restrict__ yacc) {
    __shared__ float s_cb[CH], s_da[CH], s_dt[CH];
    int s = blockIdx.x % CH;
    int h = (blockIdx.x / CH) % NH;
    int c = blockIdx.x / (CH * NH);
    int g = h >> 3;
    int p = threadIdx.x;
    const float* cbrow = &CB[(size_t)((c * NG + g) * CH + s) * CH];
    for (int i = p; i < CH; i += 64) {
        s_cb[i] = cbrow[i];
        s_da[i] = dAcs[h * T_SEQ + c * CH + i];
        s_dt[i] = dt_s[h * T_SEQ + c * CH + i];
    }
    __syncthreads();
    float das = s_da[s];
    float acc = 0.0f;
    for (int t = 0; t <= s; ++t) {
        float w = s_cb[t] * __expf(das - s_da[t]) * s_dt[t];
        acc = fmaf(w, xconv[(size_t)(c * CH + t) * CONVD + h * HD + p], acc);
    }
    acc = fmaf(Dp[h], xconv[(size_t)(c * CH + s) * CONVD + h * HD + p], acc);
    yacc[(size_t)(c * CH + s) * DIN + h * HD + p] = acc;
}

// ---------------- states[c,h,p,n] = sum_t B[c,t,g,n] * exp(dA_last-dA_t)*dt_t * x[c,t,h,p]
__global__ __launch_bounds__(256) void states_kernel(const float* __restrict__ xconv,
                                                     const float* __restrict__ dt_s,
                                                     const float* __restrict__ dAcs,
                                                     float* __restrict__ states) {
    __shared__ float bsh[CH * DSTATE];  // 128 KB
    __shared__ float w2sh[CH];
    int h = blockIdx.x % NH, c = blockIdx.x / NH;
    int g = h >> 3;
    int tid = threadIdx.x;
    for (int i = 0; i < (CH * DSTATE) / 256; ++i) {
        int flat = i * 256 + tid;
        int t = flat / DSTATE, n = flat % DSTATE;
        bsh[flat] = xconv[(size_t)(c * CH + t) * CONVD + DIN + g * DSTATE + n];
    }
    float da_last = dAcs[h * T_SEQ + c * CH + CH - 1];
    w2sh[tid] = __expf(da_last - dAcs[h * T_SEQ + c * CH + tid]) * dt_s[h * T_SEQ + c * CH + tid];
    __syncthreads();
    int p = tid & 63, nb = (tid >> 6) * 32;
    float acc[32] = {};
    for (int t = 0; t < CH; ++t) {
        float wx = w2sh[t] * xconv[(size_t)(c * CH + t) * CONVD + h * HD + p];
        const float* br = &bsh[t * DSTATE + nb];
#pragma unroll
        for (int j = 0; j < 32; ++j) acc[j] = fmaf(wx, br[j], acc[j]);
    }
    float* so = &states[((size_t)(c * NH + h) * HD + p) * DSTATE + nb];
#pragma unroll
    for (int j = 0; j < 32; ++j) so[j] = acc[j];
}

// ---------------- sequential chunk scan: prev[c] = carry before chunk c
__global__ __launch_bounds__(256) void scan_kernel(const float* __restrict__ states,
                                                   const float* __restrict__ dAcs,
                                                   float* __restrict__ prev) {
    int h = blockIdx.x;
    int base = threadIdx.x * 32;
    float carry[32] = {};
    for (int c = 0; c < NC; ++c) {
        size_t off = (size_t)(c * NH + h) * (HD * DSTATE) + base;
#pragma unroll
        for (int j = 0; j < 32; ++j) prev[off + j] = carry[j];
        float cd = __expf(dAcs[h * T_SEQ + c * CH + CH - 1]);
#pragma unroll
        for (int j = 0; j < 32; ++j) carry[j] = fmaf(carry[j], cd, states[off + j]);
    }
}

// ---------------- Y2: yacc += exp(dAcs[s]) * sum_n C[c,s,g,n]*prev[c,h,p,n]
__global__ __launch_bounds__(256) void y2_kernel(const float* __restrict__ xconv,
                                                 const float* __restrict__ prev,
                                                 const float* __restrict__ dAcs,
                                                 float* __restrict__ yacc) {
    __shared__ float psh[DSTATE * 65];  // transposed + padded
    int h = blockIdx.x % NH, c = blockIdx.x / NH;
    int g = h >> 3;
    int tid = threadIdx.x;
    size_t pbase = (size_t)(c * NH + h) * (HD * DSTATE);
    for (int i = 0; i < 32; ++i) {
        int flat = i * 256 + tid;
        int p = flat >> 7, n = flat & 127;
        psh[n * 65 + p] = prev[pbase + flat];
    }
    __syncthreads();
    int p = tid & 63, sq = tid >> 6;
    for (int si = 0; si < 64; ++si) {
        int s = sq * 64 + si;
        const float* crow = &xconv[(size_t)(c * CH + s) * CONVD + DIN + NG * DSTATE + g * DSTATE];
        float dot = 0.0f;
#pragma unroll 8
        for (int n = 0; n < DSTATE; ++n) dot = fmaf(crow[n], psh[n * 65 + p], dot);
        float e = __expf(dAcs[h * T_SEQ + c * CH + s]);
        size_t yi = (size_t)(c * CH + s) * DIN + h * HD + p;
        yacc[yi] += e * dot;
    }
}

// ---------------- gate with silu(z), grouped RMSNorm; emits bf16 for out-proj
__global__ __launch_bounds__(256) void norm_kernel(const float* __restrict__ zx,
                                                   const float* __restrict__ yacc,
                                                   const float* __restrict__ norm_w,
                                                   unsigned short* __restrict__ ynorm) {
    __shared__ float red[4];
    int t = blockIdx.x / NG, g = blockIdx.x % NG;
    int tid = threadIdx.x;
    int j1 = g * 512 + tid, j2 = j1 + 256;
    float v1 = yacc[(size_t)t * DIN + j1] * silu_f(zx[(size_t)t * DPROJP + j1]);
    float v2 = yacc[(size_t)t * DIN + j2] * silu_f(zx[(size_t)t * DPROJP + j2]);
    float ss = v1 * v1 + v2 * v2;
#pragma unroll
    for (int off = 32; off > 0; off >>= 1) ss += __shfl_down(ss, off, 64);
    if ((tid & 63) == 0) red[tid >> 6] = ss;
    __syncthreads();
    float var = (red[0] + red[1] + red[2] + red[3]) * (1.0f / 512.0f);
    float scale = rsqrtf(var + EPS);
    ynorm[(size_t)t * DIN + j1] = f2b(v1 * scale * norm_w[j1]);
    ynorm[(size_t)t * DIN + j2] = f2b(v2 * scale * norm_w[j2]);
}

extern "C" void kernel_launch(void* const* d_in, const int* in_sizes, int n_in,
                              void* d_out, int out_size, void* d_ws, size_t ws_size,
                              hipStream_t stream) {
    const float* hidden     = (const float*)d_in[0];
    const float* in_proj_w  = (const float*)d_in[1];
    const float* conv_w     = (const float*)d_in[2];
    const float* conv_b     = (const float*)d_in[3];
    const float* A          = (const float*)d_in[4];
    const float* Dp         = (const float*)d_in[5];
    const float* dt_bias    = (const float*)d_in[6];
    const float* norm_w     = (const float*)d_in[7];
    const float* out_proj_w = (const float*)d_in[8];
    float* out = (float*)d_out;

    // workspace layout (fp32 words) — total 50,855,936 words = 203.4 MB
    float* ws    = (float*)d_ws;
    float* zx    = ws;                                 // 2048*10368 = 21,233,664
    float* xconv = zx + (size_t)T_SEQ * DPROJP;        // 12,582,912
    float* dt_s  = xconv + (size_t)T_SEQ * CONVD;      // 131,072
    float* dAcs  = dt_s + (size_t)NH * T_SEQ;          // 131,072
    float* CBbuf = dAcs + (size_t)NH * T_SEQ;          // 4,194,304
    float* yacc  = CBbuf + (size_t)NC * NG * CH * CH;  // 8,388,608
    float* prev  = yacc + (size_t)T_SEQ * DIN;         // 4,194,304
    float* states = CBbuf;                             // alias: CB dead after y1
    // bf16 aliases (each region dead/not-yet-live at time of use):
    unsigned short* inw_b    = (unsigned short*)xconv; // dead once conv writes xconv
    unsigned short* hidden_b = (unsigned short*)yacc;  // dead once y1 writes yacc
    unsigned short* outw_b   = (unsigned short*)prev;  // prev dead after y2
    unsigned short* ynorm_b  = (unsigned short*)xconv; // xconv dead after y2

    // --- convert inputs to bf16
    {
        int n4s = DPROJ * DMODEL / 4, n4d = DPROJP * DMODEL / 4;
        cvt4_kernel<<<(n4d + 255) / 256, 256, 0, stream>>>((const float4*)in_proj_w, (ushort4*)inw_b, n4s, n4d);
        int h4 = T_SEQ * DMODEL / 4;
        cvt4_kernel<<<(h4 + 255) / 256, 256, 0, stream>>>((const float4*)hidden, (ushort4*)hidden_b, h4, h4);
    }
    // --- in-proj GEMM (bf16 MFMA): zx[T, DPROJP]
    gemm_bf16<128><<<dim3(DPROJP / 128, T_SEQ / 128), 256, 0, stream>>>(hidden_b, inw_b, zx, T_SEQ, DPROJP, DMODEL);

    conv_kernel<<<(T_SEQ * CONVD) / 256, 256, 0, stream>>>(zx, conv_w, conv_b, xconv);
    dt_kernel<<<NC * NH, CH, 0, stream>>>(zx, A, dt_bias, dt_s, dAcs);
    cb_kernel<<<NC * NG * CH, CH, 0, stream>>>(xconv, CBbuf);
    y1_kernel<<<NC * NH * CH, 64, 0, stream>>>(xconv, CBbuf, dt_s, dAcs, Dp, yacc);
    states_kernel<<<NC * NH, 256, 0, stream>>>(xconv, dt_s, dAcs, states);
    scan_kernel<<<NH, 256, 0, stream>>>(states, dAcs, prev);
    y2_kernel<<<NC * NH, 256, 0, stream>>>(xconv, prev, dAcs, yacc);

    // --- convert out-proj weights into prev's region (prev dead now)
    {
        int w4 = DMODEL * DIN / 4;
        cvt4_kernel<<<(w4 + 255) / 256, 256, 0, stream>>>((const float4*)out_proj_w, (ushort4*)outw_b, w4, w4);
    }
    norm_kernel<<<T_SEQ * NG, 256, 0, stream>>>(zx, yacc, norm_w, ynorm_b);
    // --- out-proj GEMM (bf16 MFMA)
    gemm_bf16<64><<<dim3(DMODEL / 64, T_SEQ / 128), 256, 0, stream>>>(ynorm_b, outw_b, out, T_SEQ, DMODEL, DIN);
}

// Round 3
// 951.979 us; speedup vs baseline: 3.1402x; 1.4694x over previous
//
#include <hip/hip_runtime.h>
#include <math.h>

#define T_SEQ 2048
#define DMODEL 2048
#define DSTATE 128
#define NH 64
#define NG 8
#define HPG 8
#define HD 64
#define CH 256
#define NC 8
#define DIN 4096
#define CONVD 6144
#define DPROJ 10304
#define DPROJP 10368   // padded to 81*128 for 128-wide MFMA tiles
#define BCW 2048       // width of bf16 B|C buffer (2*NG*DSTATE)
#define EPS 1e-5f

typedef short v8s __attribute__((ext_vector_type(8)));
typedef float v4f __attribute__((ext_vector_type(4)));

__device__ __forceinline__ float silu_f(float x) { return x / (1.0f + __expf(-x)); }

__device__ __forceinline__ unsigned short f2b(float x) {  // fp32 -> bf16 bits, RNE
    union { float f; unsigned u; } v; v.f = x;
    unsigned r = v.u + 0x7fffu + ((v.u >> 16) & 1u);
    return (unsigned short)(r >> 16);
}

// ---------------- fp32 -> bf16 convert (flat, with zero tail-padding), 4 elems/thread
__global__ __launch_bounds__(256) void cvt4_kernel(const float4* __restrict__ src,
                                                   ushort4* __restrict__ dst,
                                                   int n4_src, int n4_dst) {
    int i = blockIdx.x * 256 + threadIdx.x;
    if (i >= n4_dst) return;
    ushort4 o = {0, 0, 0, 0};
    if (i < n4_src) {
        float4 v = src[i];
        o.x = f2b(v.x); o.y = f2b(v.y); o.z = f2b(v.z); o.w = f2b(v.w);
    }
    dst[i] = o;
}

// ---------------- bf16 MFMA GEMM: C[M,N] = A[M,K] * B[N,K]^T, fp32 out
template <int BN>
__global__ __launch_bounds__(256) void gemm_bf16(const unsigned short* __restrict__ A,
                                                 const unsigned short* __restrict__ B,
                                                 float* __restrict__ C,
                                                 int M, int N, int K) {
    constexpr int BM = 128, BK = 32;
    constexpr int NWT = BN / 32;
    constexpr int BCH = (BN * BK * 2) / 1024;
    __shared__ short sA[BM * BK];
    __shared__ short sB[BN * BK];
    const int tid = threadIdx.x;
    const int wave = tid >> 6, lane = tid & 63;
    const int n0 = blockIdx.x * BN, m0 = blockIdx.y * BM;
    const int wm = (wave >> 1) * 64;
    const int wn = (wave & 1) * (BN / 2);
    const int lr = lane & 15, kq = lane >> 4;

    v4f acc[4][NWT];
#pragma unroll
    for (int i = 0; i < 4; ++i)
#pragma unroll
        for (int j = 0; j < NWT; ++j) acc[i][j] = {0.f, 0.f, 0.f, 0.f};

    for (int k0 = 0; k0 < K; k0 += BK) {
#pragma unroll
        for (int qi = 0; qi < 2; ++qi) {
            int q = wave * 2 + qi;
            int e = q * 512 + lane * 8;
            int r = e >> 5, c = e & 31;
            __builtin_amdgcn_global_load_lds(
                (const __attribute__((address_space(1))) void*)(A + (size_t)(m0 + r) * K + k0 + c),
                (__attribute__((address_space(3))) void*)(sA + q * 512), 16, 0, 0);
        }
        for (int q = wave; q < BCH; q += 4) {
            int e = q * 512 + lane * 8;
            int r = e >> 5, c = e & 31;
            __builtin_amdgcn_global_load_lds(
                (const __attribute__((address_space(1))) void*)(B + (size_t)(n0 + r) * K + k0 + c),
                (__attribute__((address_space(3))) void*)(sB + q * 512), 16, 0, 0);
        }
        __syncthreads();
        v8s af[4], bf[NWT];
#pragma unroll
        for (int i = 0; i < 4; ++i)
            af[i] = *(const v8s*)(sA + (wm + i * 16 + lr) * BK + kq * 8);
#pragma unroll
        for (int j = 0; j < NWT; ++j)
            bf[j] = *(const v8s*)(sB + (wn + j * 16 + lr) * BK + kq * 8);
#pragma unroll
        for (int i = 0; i < 4; ++i)
#pragma unroll
            for (int j = 0; j < NWT; ++j)
                acc[i][j] = __builtin_amdgcn_mfma_f32_16x16x32_bf16(af[i], bf[j], acc[i][j], 0, 0, 0);
        __syncthreads();
    }
    const int crow = kq * 4, ccol = lr;
#pragma unroll
    for (int i = 0; i < 4; ++i)
#pragma unroll
        for (int j = 0; j < NWT; ++j) {
            size_t base = (size_t)(m0 + wm + i * 16 + crow) * N + n0 + wn + j * 16 + ccol;
#pragma unroll
            for (int r = 0; r < 4; ++r) C[base + (size_t)r * N] = acc[i][j][r];
        }
}

// ---------------- causal conv1d (width 4) + SiLU; emits fp32 xconv + bf16 B|C slice
__global__ __launch_bounds__(256) void conv_kernel(const float* __restrict__ zx,
                                                   const float* __restrict__ cw,
                                                   const float* __restrict__ cb,
                                                   float* __restrict__ xconv,
                                                   unsigned short* __restrict__ BCb) {
    int idx = blockIdx.x * 256 + threadIdx.x;  // over T_SEQ*CONVD
    int c = idx % CONVD, t = idx / CONVD;
    float acc = cb[c];
#pragma unroll
    for (int k = 0; k < 4; ++k) {
        int tt = t + k - 3;
        float v = (tt >= 0) ? zx[(size_t)tt * DPROJP + DIN + c] : 0.0f;
        acc = fmaf(v, cw[c * 4 + k], acc);
    }
    float v = silu_f(acc);
    xconv[idx] = v;
    if (c >= DIN) BCb[(size_t)t * BCW + (c - DIN)] = f2b(v);
}

// ---------------- dt = softplus(dt_raw + bias); dA_cs = cumsum(dt*A) within chunk
__global__ __launch_bounds__(256) void dt_kernel(const float* __restrict__ zx,
                                                 const float* __restrict__ A,
                                                 const float* __restrict__ dt_bias,
                                                 float* __restrict__ dt_s,
                                                 float* __restrict__ dAcs) {
    __shared__ float s[CH];
    int h = blockIdx.x % NH, c = blockIdx.x / NH;
    int t = threadIdx.x;
    int tg = c * CH + t;
    float raw = zx[(size_t)tg * DPROJP + DIN + CONVD + h] + dt_bias[h];
    float dtv = (raw > 20.0f) ? raw : log1pf(__expf(raw));
    s[t] = dtv * A[h];
    __syncthreads();
    for (int off = 1; off < CH; off <<= 1) {
        float add = (t >= off) ? s[t - off] : 0.0f;
        __syncthreads();
        s[t] += add;
        __syncthreads();
    }
    dt_s[h * T_SEQ + tg] = dtv;
    dAcs[h * T_SEQ + tg] = s[t];
}

// ---------------- transpose x slice of xconv -> Xt[(c,h,p)][t] bf16 (chunk-local t)
__global__ __launch_bounds__(256) void xt_kernel(const float* __restrict__ xconv,
                                                 unsigned short* __restrict__ Xt) {
    __shared__ unsigned short sh[CH][72];
    const int h = blockIdx.x % NH, c = blockIdx.x / NH;
    const int tid = threadIdx.x;
    const int p = tid & 63, t4 = tid >> 6;
    for (int i = 0; i < 64; ++i) {
        int t = i * 4 + t4;
        sh[t][p] = f2b(xconv[(size_t)(c * CH + t) * CONVD + h * HD + p]);
    }
    __syncthreads();
    const int p2 = tid >> 2, tq = tid & 3;
    ushort4* dst = (ushort4*)(Xt + ((size_t)(c * NH + h) * HD + p2) * CH + tq * 64);
    for (int jb = 0; jb < 16; ++jb) {
        int t = tq * 64 + jb * 4;
        ushort4 v = {sh[t][p2], sh[t + 1][p2], sh[t + 2][p2], sh[t + 3][p2]};
        dst[jb] = v;
    }
}

// ---------------- fused intra-chunk: S = C·B^T (MFMA), decay/dt/causal mask,
// P·X (MFMA) + D·x. One block per (chunk, head); each wave owns interleaved s-tiles.
__global__ __launch_bounds__(256) void y1_mfma(const unsigned short* __restrict__ BCb,
                                               const unsigned short* __restrict__ Xt,
                                               const float* __restrict__ xconv,
                                               const float* __restrict__ dt_s,
                                               const float* __restrict__ dAcs,
                                               const float* __restrict__ Dp,
                                               float* __restrict__ yacc) {
    __shared__ float s_da[CH], s_dt[CH];
    __shared__ unsigned short pw[4][4][16][40];  // [wave][st_local][s16][t32 pad->40]
    const int h = blockIdx.x % NH, c = blockIdx.x / NH, g = h >> 3;
    const int tid = threadIdx.x, wave = tid >> 6, lane = tid & 63;
    const int lr = lane & 15, quad = lane >> 4;
    s_da[tid] = dAcs[h * T_SEQ + c * CH + tid];
    s_dt[tid] = dt_s[h * T_SEQ + c * CH + tid];
    __syncthreads();

    const unsigned short* Cb = BCb + (size_t)c * CH * BCW + NG * DSTATE + g * DSTATE;
    const unsigned short* Bb = BCb + (size_t)c * CH * BCW + g * DSTATE;
    const unsigned short* Xr = Xt + (size_t)(c * NH + h) * HD * CH;

    v4f Y[4][4];  // [st_local][pj]
#pragma unroll
    for (int i = 0; i < 4; ++i)
#pragma unroll
        for (int j = 0; j < 4; ++j) Y[i][j] = {0.f, 0.f, 0.f, 0.f};

    for (int tb = 0; tb < 8; ++tb) {
        if (12 + wave < 2 * tb) continue;  // this wave has no causal s-tile here
        // phase A: S-tiles = C·B^T over n (K=128), frags direct from global bf16
        v8s bfr[2][4];
#pragma unroll
        for (int j = 0; j < 2; ++j)
#pragma unroll
            for (int ks = 0; ks < 4; ++ks)
                bfr[j][ks] = *(const v8s*)(Bb + (size_t)(tb * 32 + j * 16 + lr) * BCW + ks * 32 + quad * 8);
#pragma unroll
        for (int i = 0; i < 4; ++i) {
            int st = i * 4 + wave;
            if (st < 2 * tb) continue;
            v4f S0 = {0.f, 0.f, 0.f, 0.f}, S1 = {0.f, 0.f, 0.f, 0.f};
#pragma unroll
            for (int ks = 0; ks < 4; ++ks) {
                v8s af = *(const v8s*)(Cb + (size_t)(st * 16 + lr) * BCW + ks * 32 + quad * 8);
                S0 = __builtin_amdgcn_mfma_f32_16x16x32_bf16(af, bfr[0][ks], S0, 0, 0, 0);
                S1 = __builtin_amdgcn_mfma_f32_16x16x32_bf16(af, bfr[1][ks], S1, 0, 0, 0);
            }
            // C/D layout: col t = lane&15 (+16 for S1), row s = quad*4 + r
            int t0 = tb * 32 + lr;
            float da0 = s_da[t0], dt0 = s_dt[t0];
            float da1 = s_da[t0 + 16], dt1 = s_dt[t0 + 16];
#pragma unroll
            for (int r = 0; r < 4; ++r) {
                int s = st * 16 + quad * 4 + r;
                float das = s_da[s];
                float w0 = (t0 <= s) ? S0[r] * __expf(das - da0) * dt0 : 0.f;
                float w1 = (t0 + 16 <= s) ? S1[r] * __expf(das - da1) * dt1 : 0.f;
                pw[wave][i][quad * 4 + r][lr] = f2b(w0);
                pw[wave][i][quad * 4 + r][16 + lr] = f2b(w1);
            }
        }
        // phase B: Y += P·X (K=32). B-frag from transposed Xt: contiguous v8s.
        v8s xf[4];
#pragma unroll
        for (int pj = 0; pj < 4; ++pj)
            xf[pj] = *(const v8s*)(Xr + (size_t)(pj * 16 + lr) * CH + tb * 32 + quad * 8);
#pragma unroll
        for (int i = 0; i < 4; ++i) {
            int st = i * 4 + wave;
            if (st < 2 * tb) continue;
            v8s pf = *(const v8s*)(&pw[wave][i][lr][quad * 8]);
#pragma unroll
            for (int pj = 0; pj < 4; ++pj)
                Y[i][pj] = __builtin_amdgcn_mfma_f32_16x16x32_bf16(pf, xf[pj], Y[i][pj], 0, 0, 0);
        }
    }
    // epilogue: += D*x (fp32), write yacc
    const float Dh = Dp[h];
#pragma unroll
    for (int i = 0; i < 4; ++i) {
        int st = i * 4 + wave;
#pragma unroll
        for (int pj = 0; pj < 4; ++pj) {
            int p = pj * 16 + lr;
#pragma unroll
            for (int r = 0; r < 4; ++r) {
                int s = st * 16 + quad * 4 + r;
                float v = Y[i][pj][r] + Dh * xconv[(size_t)(c * CH + s) * CONVD + h * HD + p];
                yacc[(size_t)(c * CH + s) * DIN + h * HD + p] = v;
            }
        }
    }
}

// ---------------- states[c,h,p,n] = sum_t B[c,t,g,n] * exp(dA_last-dA_t)*dt_t * x[c,t,h,p]
__global__ __launch_bounds__(256) void states_kernel(const float* __restrict__ xconv,
                                                     const float* __restrict__ dt_s,
                                                     const float* __restrict__ dAcs,
                                                     float* __restrict__ states) {
    __shared__ float bsh[CH * DSTATE];  // 128 KB
    __shared__ float w2sh[CH];
    int h = blockIdx.x % NH, c = blockIdx.x / NH;
    int g = h >> 3;
    int tid = threadIdx.x;
    for (int i = 0; i < (CH * DSTATE) / 256; ++i) {
        int flat = i * 256 + tid;
        int t = flat / DSTATE, n = flat % DSTATE;
        bsh[flat] = xconv[(size_t)(c * CH + t) * CONVD + DIN + g * DSTATE + n];
    }
    float da_last = dAcs[h * T_SEQ + c * CH + CH - 1];
    w2sh[tid] = __expf(da_last - dAcs[h * T_SEQ + c * CH + tid]) * dt_s[h * T_SEQ + c * CH + tid];
    __syncthreads();
    int p = tid & 63, nb = (tid >> 6) * 32;
    float acc[32] = {};
    for (int t = 0; t < CH; ++t) {
        float wx = w2sh[t] * xconv[(size_t)(c * CH + t) * CONVD + h * HD + p];
        const float* br = &bsh[t * DSTATE + nb];
#pragma unroll
        for (int j = 0; j < 32; ++j) acc[j] = fmaf(wx, br[j], acc[j]);
    }
    float* so = &states[((size_t)(c * NH + h) * HD + p) * DSTATE + nb];
#pragma unroll
    for (int j = 0; j < 32; ++j) so[j] = acc[j];
}

// ---------------- sequential chunk scan: prev[c] = carry before chunk c
__global__ __launch_bounds__(256) void scan_kernel(const float* __restrict__ states,
                                                   const float* __restrict__ dAcs,
                                                   float* __restrict__ prev) {
    int h = blockIdx.x;
    int base = threadIdx.x * 32;
    float carry[32] = {};
    for (int c = 0; c < NC; ++c) {
        size_t off = (size_t)(c * NH + h) * (HD * DSTATE) + base;
#pragma unroll
        for (int j = 0; j < 32; ++j) prev[off + j] = carry[j];
        float cd = __expf(dAcs[h * T_SEQ + c * CH + CH - 1]);
#pragma unroll
        for (int j = 0; j < 32; ++j) carry[j] = fmaf(carry[j], cd, states[off + j]);
    }
}

// ---------------- Y2: yacc += exp(dAcs[s]) * sum_n C[c,s,g,n]*prev[c,h,p,n]
__global__ __launch_bounds__(256) void y2_kernel(const float* __restrict__ xconv,
                                                 const float* __restrict__ prev,
                                                 const float* __restrict__ dAcs,
                                                 float* __restrict__ yacc) {
    __shared__ float psh[DSTATE * 65];  // transposed + padded
    int h = blockIdx.x % NH, c = blockIdx.x / NH;
    int g = h >> 3;
    int tid = threadIdx.x;
    size_t pbase = (size_t)(c * NH + h) * (HD * DSTATE);
    for (int i = 0; i < 32; ++i) {
        int flat = i * 256 + tid;
        int p = flat >> 7, n = flat & 127;
        psh[n * 65 + p] = prev[pbase + flat];
    }
    __syncthreads();
    int p = tid & 63, sq = tid >> 6;
    for (int si = 0; si < 64; ++si) {
        int s = sq * 64 + si;
        const float* crow = &xconv[(size_t)(c * CH + s) * CONVD + DIN + NG * DSTATE + g * DSTATE];
        float dot = 0.0f;
#pragma unroll 8
        for (int n = 0; n < DSTATE; ++n) dot = fmaf(crow[n], psh[n * 65 + p], dot);
        float e = __expf(dAcs[h * T_SEQ + c * CH + s]);
        size_t yi = (size_t)(c * CH + s) * DIN + h * HD + p;
        yacc[yi] += e * dot;
    }
}

// ---------------- gate with silu(z), grouped RMSNorm; emits bf16 for out-proj
__global__ __launch_bounds__(256) void norm_kernel(const float* __restrict__ zx,
                                                   const float* __restrict__ yacc,
                                                   const float* __restrict__ norm_w,
                                                   unsigned short* __restrict__ ynorm) {
    __shared__ float red[4];
    int t = blockIdx.x / NG, g = blockIdx.x % NG;
    int tid = threadIdx.x;
    int j1 = g * 512 + tid, j2 = j1 + 256;
    float v1 = yacc[(size_t)t * DIN + j1] * silu_f(zx[(size_t)t * DPROJP + j1]);
    float v2 = yacc[(size_t)t * DIN + j2] * silu_f(zx[(size_t)t * DPROJP + j2]);
    float ss = v1 * v1 + v2 * v2;
#pragma unroll
    for (int off = 32; off > 0; off >>= 1) ss += __shfl_down(ss, off, 64);
    if ((tid & 63) == 0) red[tid >> 6] = ss;
    __syncthreads();
    float var = (red[0] + red[1] + red[2] + red[3]) * (1.0f / 512.0f);
    float scale = rsqrtf(var + EPS);
    ynorm[(size_t)t * DIN + j1] = f2b(v1 * scale * norm_w[j1]);
    ynorm[(size_t)t * DIN + j2] = f2b(v2 * scale * norm_w[j2]);
}

extern "C" void kernel_launch(void* const* d_in, const int* in_sizes, int n_in,
                              void* d_out, int out_size, void* d_ws, size_t ws_size,
                              hipStream_t stream) {
    const float* hidden     = (const float*)d_in[0];
    const float* in_proj_w  = (const float*)d_in[1];
    const float* conv_w     = (const float*)d_in[2];
    const float* conv_b     = (const float*)d_in[3];
    const float* A          = (const float*)d_in[4];
    const float* Dp         = (const float*)d_in[5];
    const float* dt_bias    = (const float*)d_in[6];
    const float* norm_w     = (const float*)d_in[7];
    const float* out_proj_w = (const float*)d_in[8];
    float* out = (float*)d_out;

    // workspace layout (fp32 words) — total 50,855,936 words = 203.4 MB
    float* ws    = (float*)d_ws;
    float* zx    = ws;                                 // 2048*10368 = 21,233,664
    float* xconv = zx + (size_t)T_SEQ * DPROJP;        // 12,582,912
    float* dt_s  = xconv + (size_t)T_SEQ * CONVD;      // 131,072
    float* dAcs  = dt_s + (size_t)NH * T_SEQ;          // 131,072
    float* CBbuf = dAcs + (size_t)NH * T_SEQ;          // 4,194,304 (16.77 MB)
    float* yacc  = CBbuf + (size_t)NC * NG * CH * CH;  // 8,388,608
    float* prev  = yacc + (size_t)T_SEQ * DIN;         // 4,194,304 (16.77 MB)
    float* states = CBbuf;                             // alias: lives after y1_mfma
    // bf16 aliases (each region dead/not-yet-live at time of use):
    unsigned short* inw_b    = (unsigned short*)xconv; // dead once conv writes xconv
    unsigned short* hidden_b = (unsigned short*)yacc;  // dead once y1 writes yacc
    unsigned short* Xt_b     = (unsigned short*)CBbuf; // 16.77 MB exact; dead before states
    unsigned short* BCb      = (unsigned short*)prev;  // 8.4 MB; dead before scan writes prev
    unsigned short* outw_b   = (unsigned short*)prev;  // prev dead after y2
    unsigned short* ynorm_b  = (unsigned short*)xconv; // xconv dead after y2

    // --- convert inputs to bf16
    {
        int n4s = DPROJ * DMODEL / 4, n4d = DPROJP * DMODEL / 4;
        cvt4_kernel<<<(n4d + 255) / 256, 256, 0, stream>>>((const float4*)in_proj_w, (ushort4*)inw_b, n4s, n4d);
        int h4 = T_SEQ * DMODEL / 4;
        cvt4_kernel<<<(h4 + 255) / 256, 256, 0, stream>>>((const float4*)hidden, (ushort4*)hidden_b, h4, h4);
    }
    // --- in-proj GEMM (bf16 MFMA): zx[T, DPROJP]
    gemm_bf16<128><<<dim3(DPROJP / 128, T_SEQ / 128), 256, 0, stream>>>(hidden_b, inw_b, zx, T_SEQ, DPROJP, DMODEL);

    conv_kernel<<<(T_SEQ * CONVD) / 256, 256, 0, stream>>>(zx, conv_w, conv_b, xconv, BCb);
    dt_kernel<<<NC * NH, CH, 0, stream>>>(zx, A, dt_bias, dt_s, dAcs);
    xt_kernel<<<NC * NH, 256, 0, stream>>>(xconv, Xt_b);
    y1_mfma<<<NC * NH, 256, 0, stream>>>(BCb, Xt_b, xconv, dt_s, dAcs, Dp, yacc);
    states_kernel<<<NC * NH, 256, 0, stream>>>(xconv, dt_s, dAcs, states);
    scan_kernel<<<NH, 256, 0, stream>>>(states, dAcs, prev);
    y2_kernel<<<NC * NH, 256, 0, stream>>>(xconv, prev, dAcs, yacc);

    // --- convert out-proj weights into prev's region (prev dead now)
    {
        int w4 = DMODEL * DIN / 4;
        cvt4_kernel<<<(w4 + 255) / 256, 256, 0, stream>>>((const float4*)out_proj_w, (ushort4*)outw_b, w4, w4);
    }
    norm_kernel<<<T_SEQ * NG, 256, 0, stream>>>(zx, yacc, norm_w, ynorm_b);
    // --- out-proj GEMM (bf16 MFMA)
    gemm_bf16<64><<<dim3(DMODEL / 64, T_SEQ / 128), 256, 0, stream>>>(ynorm_b, outw_b, out, T_SEQ, DMODEL, DIN);
}

// Round 4
// 608.669 us; speedup vs baseline: 4.9113x; 1.5640x over previous
//
#include <hip/hip_runtime.h>
#include <math.h>

#define T_SEQ 2048
#define DMODEL 2048
#define DSTATE 128
#define NH 64
#define NG 8
#define HPG 8
#define HD 64
#define CH 256
#define NC 8
#define DIN 4096
#define CONVD 6144
#define DPROJ 10304
#define DPROJP 10368   // padded to 81*128 for 128-wide MFMA tiles
#define BCW 2048       // width of bf16 B|C buffer (2*NG*DSTATE)
#define EPS 1e-5f

typedef short v8s __attribute__((ext_vector_type(8)));
typedef float v4f __attribute__((ext_vector_type(4)));

__device__ __forceinline__ float silu_f(float x) { return x / (1.0f + __expf(-x)); }

__device__ __forceinline__ unsigned short f2b(float x) {  // fp32 -> bf16 bits, RNE
    union { float f; unsigned u; } v; v.f = x;
    unsigned r = v.u + 0x7fffu + ((v.u >> 16) & 1u);
    return (unsigned short)(r >> 16);
}
__device__ __forceinline__ float b2f(unsigned short u) {
    union { unsigned u; float f; } v; v.u = ((unsigned)u) << 16; return v.f;
}

// ---------------- fp32 -> bf16 convert (flat, with zero tail-padding), 4 elems/thread
__global__ __launch_bounds__(256) void cvt4_kernel(const float4* __restrict__ src,
                                                   ushort4* __restrict__ dst,
                                                   int n4_src, int n4_dst) {
    int i = blockIdx.x * 256 + threadIdx.x;
    if (i >= n4_dst) return;
    ushort4 o = {0, 0, 0, 0};
    if (i < n4_src) {
        float4 v = src[i];
        o.x = f2b(v.x); o.y = f2b(v.y); o.z = f2b(v.z); o.w = f2b(v.w);
    }
    dst[i] = o;
}

// ---------------- bf16 MFMA GEMM: C[M,N] = A[M,K] * B[N,K]^T, fp32 out
template <int BN>
__global__ __launch_bounds__(256) void gemm_bf16(const unsigned short* __restrict__ A,
                                                 const unsigned short* __restrict__ B,
                                                 float* __restrict__ C,
                                                 int M, int N, int K) {
    constexpr int BM = 128, BK = 32;
    constexpr int NWT = BN / 32;
    constexpr int BCH = (BN * BK * 2) / 1024;
    __shared__ short sA[BM * BK];
    __shared__ short sB[BN * BK];
    const int tid = threadIdx.x;
    const int wave = tid >> 6, lane = tid & 63;
    const int n0 = blockIdx.x * BN, m0 = blockIdx.y * BM;
    const int wm = (wave >> 1) * 64;
    const int wn = (wave & 1) * (BN / 2);
    const int lr = lane & 15, kq = lane >> 4;

    v4f acc[4][NWT];
#pragma unroll
    for (int i = 0; i < 4; ++i)
#pragma unroll
        for (int j = 0; j < NWT; ++j) acc[i][j] = {0.f, 0.f, 0.f, 0.f};

    for (int k0 = 0; k0 < K; k0 += BK) {
#pragma unroll
        for (int qi = 0; qi < 2; ++qi) {
            int q = wave * 2 + qi;
            int e = q * 512 + lane * 8;
            int r = e >> 5, c = e & 31;
            __builtin_amdgcn_global_load_lds(
                (const __attribute__((address_space(1))) void*)(A + (size_t)(m0 + r) * K + k0 + c),
                (__attribute__((address_space(3))) void*)(sA + q * 512), 16, 0, 0);
        }
        for (int q = wave; q < BCH; q += 4) {
            int e = q * 512 + lane * 8;
            int r = e >> 5, c = e & 31;
            __builtin_amdgcn_global_load_lds(
                (const __attribute__((address_space(1))) void*)(B + (size_t)(n0 + r) * K + k0 + c),
                (__attribute__((address_space(3))) void*)(sB + q * 512), 16, 0, 0);
        }
        __syncthreads();
        v8s af[4], bf[NWT];
#pragma unroll
        for (int i = 0; i < 4; ++i)
            af[i] = *(const v8s*)(sA + (wm + i * 16 + lr) * BK + kq * 8);
#pragma unroll
        for (int j = 0; j < NWT; ++j)
            bf[j] = *(const v8s*)(sB + (wn + j * 16 + lr) * BK + kq * 8);
#pragma unroll
        for (int i = 0; i < 4; ++i)
#pragma unroll
            for (int j = 0; j < NWT; ++j)
                acc[i][j] = __builtin_amdgcn_mfma_f32_16x16x32_bf16(af[i], bf[j], acc[i][j], 0, 0, 0);
        __syncthreads();
    }
    const int crow = kq * 4, ccol = lr;
#pragma unroll
    for (int i = 0; i < 4; ++i)
#pragma unroll
        for (int j = 0; j < NWT; ++j) {
            size_t base = (size_t)(m0 + wm + i * 16 + crow) * N + n0 + wn + j * 16 + ccol;
#pragma unroll
            for (int r = 0; r < 4; ++r) C[base + (size_t)r * N] = acc[i][j][r];
        }
}

// ---------------- causal conv1d (width 4) + SiLU; emits fp32 xconv + bf16 B|C slice
// + bf16 transposed B slice Btr[c,g,n,t_local]
__global__ __launch_bounds__(256) void conv_kernel(const float* __restrict__ zx,
                                                   const float* __restrict__ cw,
                                                   const float* __restrict__ cb,
                                                   float* __restrict__ xconv,
                                                   unsigned short* __restrict__ BCb,
                                                   unsigned short* __restrict__ Btr) {
    int idx = blockIdx.x * 256 + threadIdx.x;  // over T_SEQ*CONVD
    int c = idx % CONVD, t = idx / CONVD;
    float acc = cb[c];
#pragma unroll
    for (int k = 0; k < 4; ++k) {
        int tt = t + k - 3;
        float v = (tt >= 0) ? zx[(size_t)tt * DPROJP + DIN + c] : 0.0f;
        acc = fmaf(v, cw[c * 4 + k], acc);
    }
    float v = silu_f(acc);
    xconv[idx] = v;
    if (c >= DIN) {
        unsigned short b = f2b(v);
        BCb[(size_t)t * BCW + (c - DIN)] = b;
        int bc = c - DIN;
        if (bc < NG * DSTATE) {  // B slice: scatter transposed
            int cc = t >> 8, tl = t & 255;
            Btr[((size_t)cc * (NG * DSTATE) + bc) * CH + tl] = b;
        }
    }
}

// ---------------- dt = softplus(dt_raw + bias); dA_cs = cumsum(dt*A) within chunk
__global__ __launch_bounds__(256) void dt_kernel(const float* __restrict__ zx,
                                                 const float* __restrict__ A,
                                                 const float* __restrict__ dt_bias,
                                                 float* __restrict__ dt_s,
                                                 float* __restrict__ dAcs) {
    __shared__ float s[CH];
    int h = blockIdx.x % NH, c = blockIdx.x / NH;
    int t = threadIdx.x;
    int tg = c * CH + t;
    float raw = zx[(size_t)tg * DPROJP + DIN + CONVD + h] + dt_bias[h];
    float dtv = (raw > 20.0f) ? raw : log1pf(__expf(raw));
    s[t] = dtv * A[h];
    __syncthreads();
    for (int off = 1; off < CH; off <<= 1) {
        float add = (t >= off) ? s[t - off] : 0.0f;
        __syncthreads();
        s[t] += add;
        __syncthreads();
    }
    dt_s[h * T_SEQ + tg] = dtv;
    dAcs[h * T_SEQ + tg] = s[t];
}

// ---------------- transpose x slice of xconv -> Xt[(c,h,p)][t] bf16 (chunk-local t)
__global__ __launch_bounds__(256) void xt_kernel(const float* __restrict__ xconv,
                                                 unsigned short* __restrict__ Xt) {
    __shared__ unsigned short sh[CH][72];
    const int h = blockIdx.x % NH, c = blockIdx.x / NH;
    const int tid = threadIdx.x;
    const int p = tid & 63, t4 = tid >> 6;
    for (int i = 0; i < 64; ++i) {
        int t = i * 4 + t4;
        sh[t][p] = f2b(xconv[(size_t)(c * CH + t) * CONVD + h * HD + p]);
    }
    __syncthreads();
    const int p2 = tid >> 2, tq = tid & 3;
    ushort4* dst = (ushort4*)(Xt + ((size_t)(c * NH + h) * HD + p2) * CH + tq * 64);
    for (int jb = 0; jb < 16; ++jb) {
        int t = tq * 64 + jb * 4;
        ushort4 v = {sh[t][p2], sh[t + 1][p2], sh[t + 2][p2], sh[t + 3][p2]};
        dst[jb] = v;
    }
}

// ---------------- fused intra-chunk: S = C·B^T (MFMA), decay/dt/causal mask, P·X (MFMA) + D·x
__global__ __launch_bounds__(256) void y1_mfma(const unsigned short* __restrict__ BCb,
                                               const unsigned short* __restrict__ Xt,
                                               const float* __restrict__ xconv,
                                               const float* __restrict__ dt_s,
                                               const float* __restrict__ dAcs,
                                               const float* __restrict__ Dp,
                                               float* __restrict__ yacc) {
    __shared__ float s_da[CH], s_dt[CH];
    __shared__ unsigned short pw[4][4][16][40];
    const int h = blockIdx.x % NH, c = blockIdx.x / NH, g = h >> 3;
    const int tid = threadIdx.x, wave = tid >> 6, lane = tid & 63;
    const int lr = lane & 15, quad = lane >> 4;
    s_da[tid] = dAcs[h * T_SEQ + c * CH + tid];
    s_dt[tid] = dt_s[h * T_SEQ + c * CH + tid];
    __syncthreads();

    const unsigned short* Cb = BCb + (size_t)c * CH * BCW + NG * DSTATE + g * DSTATE;
    const unsigned short* Bb = BCb + (size_t)c * CH * BCW + g * DSTATE;
    const unsigned short* Xr = Xt + (size_t)(c * NH + h) * HD * CH;

    v4f Y[4][4];
#pragma unroll
    for (int i = 0; i < 4; ++i)
#pragma unroll
        for (int j = 0; j < 4; ++j) Y[i][j] = {0.f, 0.f, 0.f, 0.f};

    for (int tb = 0; tb < 8; ++tb) {
        if (12 + wave < 2 * tb) continue;
        v8s bfr[2][4];
#pragma unroll
        for (int j = 0; j < 2; ++j)
#pragma unroll
            for (int ks = 0; ks < 4; ++ks)
                bfr[j][ks] = *(const v8s*)(Bb + (size_t)(tb * 32 + j * 16 + lr) * BCW + ks * 32 + quad * 8);
#pragma unroll
        for (int i = 0; i < 4; ++i) {
            int st = i * 4 + wave;
            if (st < 2 * tb) continue;
            v4f S0 = {0.f, 0.f, 0.f, 0.f}, S1 = {0.f, 0.f, 0.f, 0.f};
#pragma unroll
            for (int ks = 0; ks < 4; ++ks) {
                v8s af = *(const v8s*)(Cb + (size_t)(st * 16 + lr) * BCW + ks * 32 + quad * 8);
                S0 = __builtin_amdgcn_mfma_f32_16x16x32_bf16(af, bfr[0][ks], S0, 0, 0, 0);
                S1 = __builtin_amdgcn_mfma_f32_16x16x32_bf16(af, bfr[1][ks], S1, 0, 0, 0);
            }
            int t0 = tb * 32 + lr;
            float da0 = s_da[t0], dt0 = s_dt[t0];
            float da1 = s_da[t0 + 16], dt1 = s_dt[t0 + 16];
#pragma unroll
            for (int r = 0; r < 4; ++r) {
                int s = st * 16 + quad * 4 + r;
                float das = s_da[s];
                float w0 = (t0 <= s) ? S0[r] * __expf(das - da0) * dt0 : 0.f;
                float w1 = (t0 + 16 <= s) ? S1[r] * __expf(das - da1) * dt1 : 0.f;
                pw[wave][i][quad * 4 + r][lr] = f2b(w0);
                pw[wave][i][quad * 4 + r][16 + lr] = f2b(w1);
            }
        }
        v8s xf[4];
#pragma unroll
        for (int pj = 0; pj < 4; ++pj)
            xf[pj] = *(const v8s*)(Xr + (size_t)(pj * 16 + lr) * CH + tb * 32 + quad * 8);
#pragma unroll
        for (int i = 0; i < 4; ++i) {
            int st = i * 4 + wave;
            if (st < 2 * tb) continue;
            v8s pf = *(const v8s*)(&pw[wave][i][lr][quad * 8]);
#pragma unroll
            for (int pj = 0; pj < 4; ++pj)
                Y[i][pj] = __builtin_amdgcn_mfma_f32_16x16x32_bf16(pf, xf[pj], Y[i][pj], 0, 0, 0);
        }
    }
    const float Dh = Dp[h];
#pragma unroll
    for (int i = 0; i < 4; ++i) {
        int st = i * 4 + wave;
#pragma unroll
        for (int pj = 0; pj < 4; ++pj) {
            int p = pj * 16 + lr;
#pragma unroll
            for (int r = 0; r < 4; ++r) {
                int s = st * 16 + quad * 4 + r;
                float v = Y[i][pj][r] + Dh * xconv[(size_t)(c * CH + s) * CONVD + h * HD + p];
                yacc[(size_t)(c * CH + s) * DIN + h * HD + p] = v;
            }
        }
    }
}

// ---------------- MFMA states: states[c,h,p,n] = sum_t Xt[p,t] * (w2[t]*Btr[n,t])
__global__ __launch_bounds__(256) void states_mfma(const unsigned short* __restrict__ Xt,
                                                   const unsigned short* __restrict__ Btr,
                                                   const float* __restrict__ dt_s,
                                                   const float* __restrict__ dAcs,
                                                   float* __restrict__ states) {
    __shared__ float w2sh[CH];
    const int h = blockIdx.x % NH, c = blockIdx.x / NH, g = h >> 3;
    const int tid = threadIdx.x, wave = tid >> 6, lane = tid & 63;
    const int lr = lane & 15, quad = lane >> 4;
    float da_last = dAcs[h * T_SEQ + c * CH + CH - 1];
    w2sh[tid] = __expf(da_last - dAcs[h * T_SEQ + c * CH + tid]) * dt_s[h * T_SEQ + c * CH + tid];
    __syncthreads();
    const unsigned short* Xr = Xt + (size_t)(c * NH + h) * HD * CH;
    const unsigned short* Br = Btr + (size_t)(c * NG + g) * DSTATE * CH;

    v4f acc[4][2];
#pragma unroll
    for (int i = 0; i < 4; ++i)
#pragma unroll
        for (int j = 0; j < 2; ++j) acc[i][j] = {0.f, 0.f, 0.f, 0.f};

    for (int kb = 0; kb < 8; ++kb) {
        const int t0 = kb * 32 + quad * 8;
        float w[8];
        {
            float4 wa = *(const float4*)&w2sh[t0];
            float4 wb = *(const float4*)&w2sh[t0 + 4];
            w[0] = wa.x; w[1] = wa.y; w[2] = wa.z; w[3] = wa.w;
            w[4] = wb.x; w[5] = wb.y; w[6] = wb.z; w[7] = wb.w;
        }
        v8s bf[2];
#pragma unroll
        for (int j = 0; j < 2; ++j) {
            v8s raw = *(const v8s*)(Br + (size_t)(wave * 32 + j * 16 + lr) * CH + t0);
            v8s o;
#pragma unroll
            for (int e = 0; e < 8; ++e) o[e] = (short)f2b(b2f((unsigned short)raw[e]) * w[e]);
            bf[j] = o;
        }
        v8s af[4];
#pragma unroll
        for (int i = 0; i < 4; ++i)
            af[i] = *(const v8s*)(Xr + (size_t)(i * 16 + lr) * CH + t0);
#pragma unroll
        for (int i = 0; i < 4; ++i)
#pragma unroll
            for (int j = 0; j < 2; ++j)
                acc[i][j] = __builtin_amdgcn_mfma_f32_16x16x32_bf16(af[i], bf[j], acc[i][j], 0, 0, 0);
    }
    // D layout: row p = i*16 + quad*4 + r, col n = wave*32 + j*16 + lr
#pragma unroll
    for (int i = 0; i < 4; ++i)
#pragma unroll
        for (int j = 0; j < 2; ++j)
#pragma unroll
            for (int r = 0; r < 4; ++r)
                states[((size_t)(c * NH + h) * HD + i * 16 + quad * 4 + r) * DSTATE +
                       wave * 32 + j * 16 + lr] = acc[i][j][r];
}

// ---------------- sequential chunk scan: prev_b[c] (bf16) = carry before chunk c
__global__ __launch_bounds__(256) void scan_kernel(const float* __restrict__ states,
                                                   const float* __restrict__ dAcs,
                                                   unsigned short* __restrict__ prev_b) {
    int h = blockIdx.x;
    int base = threadIdx.x * 32;
    float carry[32] = {};
    for (int c = 0; c < NC; ++c) {
        size_t off = (size_t)(c * NH + h) * (HD * DSTATE) + base;
#pragma unroll
        for (int j = 0; j < 32; ++j) prev_b[off + j] = f2b(carry[j]);
        float cd = __expf(dAcs[h * T_SEQ + c * CH + CH - 1]);
#pragma unroll
        for (int j = 0; j < 32; ++j) carry[j] = fmaf(carry[j], cd, states[off + j]);
    }
}

// ---------------- MFMA Y2: yacc[s,p] += exp(dAcs[s]) * sum_n Cb[s,n]*prev_b[p,n]
__global__ __launch_bounds__(256) void y2_mfma(const unsigned short* __restrict__ BCb,
                                               const unsigned short* __restrict__ prev_b,
                                               const float* __restrict__ dAcs,
                                               float* __restrict__ yacc) {
    __shared__ float s_da[CH];
    const int h = blockIdx.x % NH, c = blockIdx.x / NH, g = h >> 3;
    const int tid = threadIdx.x, wave = tid >> 6, lane = tid & 63;
    const int lr = lane & 15, quad = lane >> 4;
    s_da[tid] = dAcs[h * T_SEQ + c * CH + tid];
    __syncthreads();
    const unsigned short* Cb = BCb + (size_t)c * CH * BCW + NG * DSTATE + g * DSTATE;
    const unsigned short* Pr = prev_b + (size_t)(c * NH + h) * HD * DSTATE;

    v4f acc[4][4];
#pragma unroll
    for (int i = 0; i < 4; ++i)
#pragma unroll
        for (int j = 0; j < 4; ++j) acc[i][j] = {0.f, 0.f, 0.f, 0.f};

#pragma unroll
    for (int kb = 0; kb < 4; ++kb) {
        const int n0 = kb * 32 + quad * 8;
        v8s bfp[4];
#pragma unroll
        for (int pj = 0; pj < 4; ++pj)
            bfp[pj] = *(const v8s*)(Pr + (size_t)(pj * 16 + lr) * DSTATE + n0);
#pragma unroll
        for (int i = 0; i < 4; ++i) {
            v8s af = *(const v8s*)(Cb + (size_t)((wave * 4 + i) * 16 + lr) * BCW + n0);
#pragma unroll
            for (int pj = 0; pj < 4; ++pj)
                acc[i][pj] = __builtin_amdgcn_mfma_f32_16x16x32_bf16(af, bfp[pj], acc[i][pj], 0, 0, 0);
        }
    }
#pragma unroll
    for (int i = 0; i < 4; ++i) {
#pragma unroll
        for (int r = 0; r < 4; ++r) {
            int s = (wave * 4 + i) * 16 + quad * 4 + r;
            float e = __expf(s_da[s]);
            size_t base = (size_t)(c * CH + s) * DIN + h * HD;
#pragma unroll
            for (int pj = 0; pj < 4; ++pj) {
                int p = pj * 16 + lr;
                yacc[base + p] += e * acc[i][pj][r];
            }
        }
    }
}

// ---------------- gate with silu(z), grouped RMSNorm; emits bf16 for out-proj
__global__ __launch_bounds__(256) void norm_kernel(const float* __restrict__ zx,
                                                   const float* __restrict__ yacc,
                                                   const float* __restrict__ norm_w,
                                                   unsigned short* __restrict__ ynorm) {
    __shared__ float red[4];
    int t = blockIdx.x / NG, g = blockIdx.x % NG;
    int tid = threadIdx.x;
    int j1 = g * 512 + tid, j2 = j1 + 256;
    float v1 = yacc[(size_t)t * DIN + j1] * silu_f(zx[(size_t)t * DPROJP + j1]);
    float v2 = yacc[(size_t)t * DIN + j2] * silu_f(zx[(size_t)t * DPROJP + j2]);
    float ss = v1 * v1 + v2 * v2;
#pragma unroll
    for (int off = 32; off > 0; off >>= 1) ss += __shfl_down(ss, off, 64);
    if ((tid & 63) == 0) red[tid >> 6] = ss;
    __syncthreads();
    float var = (red[0] + red[1] + red[2] + red[3]) * (1.0f / 512.0f);
    float scale = rsqrtf(var + EPS);
    ynorm[(size_t)t * DIN + j1] = f2b(v1 * scale * norm_w[j1]);
    ynorm[(size_t)t * DIN + j2] = f2b(v2 * scale * norm_w[j2]);
}

extern "C" void kernel_launch(void* const* d_in, const int* in_sizes, int n_in,
                              void* d_out, int out_size, void* d_ws, size_t ws_size,
                              hipStream_t stream) {
    const float* hidden     = (const float*)d_in[0];
    const float* in_proj_w  = (const float*)d_in[1];
    const float* conv_w     = (const float*)d_in[2];
    const float* conv_b     = (const float*)d_in[3];
    const float* A          = (const float*)d_in[4];
    const float* Dp         = (const float*)d_in[5];
    const float* dt_bias    = (const float*)d_in[6];
    const float* norm_w     = (const float*)d_in[7];
    const float* out_proj_w = (const float*)d_in[8];
    float* out = (float*)d_out;

    // workspace layout (fp32 words) — total 50,855,936 words = 203.4 MB
    float* ws    = (float*)d_ws;
    float* zx    = ws;                                 // 21,233,664
    float* xcreg = zx + (size_t)T_SEQ * DPROJP;        // 12,582,912 (xconv region)
    float* dt_s  = xcreg + (size_t)T_SEQ * CONVD;      // 131,072
    float* dAcs  = dt_s + (size_t)NH * T_SEQ;          // 131,072
    float* cbreg = dAcs + (size_t)NH * T_SEQ;          // 4,194,304 (Xt region)
    float* yacc  = cbreg + (size_t)NC * NG * CH * CH;  // 8,388,608
    float* preg  = yacc + (size_t)T_SEQ * DIN;         // 4,194,304

    float* xconv  = xcreg;                             // live conv -> y1
    float* states = xcreg;                             // live states_mfma -> scan (after y1)
    // bf16 aliases (each region dead/not-yet-live at time of use):
    unsigned short* inw_b    = (unsigned short*)xcreg;              // dead when conv writes
    unsigned short* hidden_b = (unsigned short*)yacc;               // dead after in-proj
    unsigned short* Xt_b     = (unsigned short*)cbreg;              // xt -> states_mfma
    unsigned short* BCb      = (unsigned short*)preg;               // conv -> y2 (8.4 MB)
    unsigned short* Btr      = (unsigned short*)(preg + 2097152);   // conv -> states_mfma (4 MB)
    unsigned short* prev_b   = (unsigned short*)(preg + 2097152);   // scan -> y2 (8.4 MB, over dead Btr)
    unsigned short* outw_b   = (unsigned short*)preg;               // after y2 (16.8 MB)
    unsigned short* ynorm_b  = (unsigned short*)xcreg;              // norm -> out-proj (after scan)

    // --- convert inputs to bf16
    {
        int n4s = DPROJ * DMODEL / 4, n4d = DPROJP * DMODEL / 4;
        cvt4_kernel<<<(n4d + 255) / 256, 256, 0, stream>>>((const float4*)in_proj_w, (ushort4*)inw_b, n4s, n4d);
        int h4 = T_SEQ * DMODEL / 4;
        cvt4_kernel<<<(h4 + 255) / 256, 256, 0, stream>>>((const float4*)hidden, (ushort4*)hidden_b, h4, h4);
    }
    // --- in-proj GEMM (bf16 MFMA): zx[T, DPROJP]
    gemm_bf16<128><<<dim3(DPROJP / 128, T_SEQ / 128), 256, 0, stream>>>(hidden_b, inw_b, zx, T_SEQ, DPROJP, DMODEL);

    conv_kernel<<<(T_SEQ * CONVD) / 256, 256, 0, stream>>>(zx, conv_w, conv_b, xconv, BCb, Btr);
    dt_kernel<<<NC * NH, CH, 0, stream>>>(zx, A, dt_bias, dt_s, dAcs);
    xt_kernel<<<NC * NH, 256, 0, stream>>>(xconv, Xt_b);
    y1_mfma<<<NC * NH, 256, 0, stream>>>(BCb, Xt_b, xconv, dt_s, dAcs, Dp, yacc);
    states_mfma<<<NC * NH, 256, 0, stream>>>(Xt_b, Btr, dt_s, dAcs, states);
    scan_kernel<<<NH, 256, 0, stream>>>(states, dAcs, prev_b);
    y2_mfma<<<NC * NH, 256, 0, stream>>>(BCb, prev_b, dAcs, yacc);

    // --- convert out-proj weights into preg (BCb/prev_b dead now)
    {
        int w4 = DMODEL * DIN / 4;
        cvt4_kernel<<<(w4 + 255) / 256, 256, 0, stream>>>((const float4*)out_proj_w, (ushort4*)outw_b, w4, w4);
    }
    norm_kernel<<<T_SEQ * NG, 256, 0, stream>>>(zx, yacc, norm_w, ynorm_b);
    // --- out-proj GEMM (bf16 MFMA)
    gemm_bf16<64><<<dim3(DMODEL / 64, T_SEQ / 128), 256, 0, stream>>>(ynorm_b, outw_b, out, T_SEQ, DMODEL, DIN);
}